// Round 5
// baseline (186.863 us; speedup 1.0000x reference)
//
#include <hip/hip_runtime.h>

// DetectionLoss: B=32768, G=7, A=2, C=3, M=20.
// R7 (resubmit — previous round hit GPUAcquisitionTimeout, never benched).
// SPLIT the monolithic block. Evidence: R3 (awful stride) == R6 (perfect
// coalescing) == 61us, occupancy 39.6%, VALUBusy 14.6%, HBM 13.5% -> the
// phase structure (barriers + dedup + positives tail fused around the stream)
// pins the kernel, not the access pattern. Harness overhead decoded: dur_us =
// ~120us of 401MB poison-fills (fixed) + our kernels; budget = kernel time.
//  - det_loss_assign (1024 x 448): R6 Phases 1/1b/2b verbatim — target
//    assignment, last-write-wins dedup, compacted positives (obj/bbox/cls +
//    noobj correction -sp(obj)). ~33MB traffic.
//  - det_loss_noobj (2048 x 256): pure grid-stride float4 stream over ALL of
//    preds (103MB), no LDS/barriers/divergence, 32 waves/CU. Sums sp(v.x) on
//    even-parity lanes (chunk parity == gtid parity; stride is even).
//  - det_loss_reduce: sums [5][NT] partials, applies weights / num_pos.

namespace {
constexpr int kG = 7;
constexpr int kA = 2;
constexpr int kM = 20;
constexpr int kCells = kG * kG * kA;     // 98
constexpr int kCh = 8;                   // 5 + C
constexpr int kNB = 32;                  // batches per assign-block
constexpr int kBlockA = 448;             // 7 waves
constexpr int kTgt = kNB * kM;           // 640
constexpr int kBlockN = 256;             // noobj stream block
constexpr int kGridN = 2048;             // 8 blocks/CU * 4 waves = 32 waves/CU
}

__device__ __forceinline__ float softplus_fast(float x) {
    // logaddexp(x,0); fast exp/log — absmax threshold leaves huge slack
    return fmaxf(x, 0.0f) + __logf(1.0f + __expf(-fabsf(x)));
}

// ---------------- Kernel A: assignment + positives ----------------
__global__ __launch_bounds__(kBlockA) void det_loss_assign(
    const float* __restrict__ preds,
    const float* __restrict__ tboxes,
    const int* __restrict__ tlabels,
    const int* __restrict__ nobjs,
    const float* __restrict__ anchors,
    const float* __restrict__ cweights,
    float* __restrict__ partial,   // SoA [5][NT]; this kernel owns cols [0, gridDim.x)
    int B, int NT)
{
    __shared__ float4 s_tv[kTgt];        // per-target (tx,ty,tw,th)
    __shared__ short  s_cell[kTgt];      // block-local cell = bl*98+c, -1 invalid
    __shared__ int    s_pos[kTgt];       // compacted winners: (j<<16)|cell
    __shared__ int    s_nobj[kNB];
    __shared__ int    s_npos;
    __shared__ float  s_red[kBlockA / 64][4];

    const int tid = threadIdx.x;
    const int b0 = blockIdx.x * kNB;

    if (tid < kNB) {
        const int b = b0 + tid;
        s_nobj[tid] = (b < B) ? nobjs[b] : 0;
    }
    if (tid == 0) s_npos = 0;
    __syncthreads();

    const float a00 = anchors[0], a01 = anchors[1];
    const float a10 = anchors[2], a11 = anchors[3];

    // ---- Phase 1: per-target assignment ----
    for (int j = tid; j < kTgt; j += kBlockA) {
        const int bl = j / kM;
        const int m  = j - bl * kM;
        short cell = -1;
        float4 tv = make_float4(0.f, 0.f, 0.f, 0.f);
        if (b0 + bl < B) {
            const float4 box = ((const float4*)tboxes)[(size_t)b0 * kM + j];
            const float x1 = box.x, y1 = box.y, x2 = box.z, y2 = box.w;
            const float cx = (x1 + x2) * 0.5f, cy = (y1 + y2) * 0.5f;
            const float w = x2 - x1, h = y2 - y1;
            if (w > 0.f && h > 0.f && m < s_nobj[bl]) {
                const int gi = min(max((int)floorf(cy * (float)kG), 0), kG - 1);
                const int gj = min(max((int)floorf(cx * (float)kG), 0), kG - 1);
                const float wg = w * (float)kG, hg = h * (float)kG;
                const float i0 = fminf(wg, a00) * fminf(hg, a01);
                const float u0 = wg * hg + a00 * a01 - i0;
                const float r0 = i0 / (u0 + 1e-6f);
                const float i1 = fminf(wg, a10) * fminf(hg, a11);
                const float u1 = wg * hg + a10 * a11 - i1;
                const float r1 = i1 / (u1 + 1e-6f);
                const int a = (r1 > r0) ? 1 : 0;   // argmax, first-max wins
                const float aw = a ? a10 : a00;
                const float ah = a ? a11 : a01;
                tv.x = cx * (float)kG - (float)gj;
                tv.y = cy * (float)kG - (float)gi;
                tv.z = __logf(fmaxf(wg, 0.01f) / (aw + 1e-6f));
                tv.w = __logf(fmaxf(hg, 0.01f) / (ah + 1e-6f));
                cell = (short)(bl * kCells + (gi * kG + gj) * kA + a);
            }
        }
        s_cell[j] = cell;
        s_tv[j] = tv;
    }
    __syncthreads();

    // ---- Phase 1b: dedup (last-write-wins) + compaction ----
    for (int j = tid; j < kTgt; j += kBlockA) {
        const short c = s_cell[j];
        if (c >= 0) {
            const int bl = j / kM;
            const int m  = j - bl * kM;
            bool win = true;
            for (int m2 = m + 1; m2 < kM; ++m2) {
                if (s_cell[bl * kM + m2] == c) { win = false; break; }
            }
            if (win) {
                const int idx = atomicAdd(&s_npos, 1);
                s_pos[idx] = (j << 16) | (int)c;
            }
        }
    }
    __syncthreads();

    // ---- Phase 2b: compacted positives ----
    float accO = 0.f, accN = 0.f, accB = 0.f, accC = 0.f;
    const float* __restrict__ pblk = preds + (size_t)b0 * kCells * kCh;
    const int np = s_npos;
    const float cw0 = cweights[0], cw1 = cweights[1], cw2 = cweights[2];
    for (int t = tid; t < np; t += kBlockA) {
        const int pk = s_pos[t];
        const int j  = pk >> 16;
        const int ci = pk & 0xFFFF;
        const float4* pc = (const float4*)(pblk + (size_t)ci * kCh);
        const float4 p0 = pc[0];
        const float4 p1 = pc[1];
        const float spp = softplus_fast(p0.x);
        accN -= spp;            // remove noobj term the stream kernel adds
        accO += spp - p0.x;     // softplus(-x) == softplus(x) - x
        const float4 tv = s_tv[j];
        float d, ad;
        d = p0.y - tv.x; ad = fabsf(d); accB += (ad < 1.f) ? 0.5f * d * d : ad - 0.5f;
        d = p0.z - tv.y; ad = fabsf(d); accB += (ad < 1.f) ? 0.5f * d * d : ad - 0.5f;
        d = p0.w - tv.z; ad = fabsf(d); accB += (ad < 1.f) ? 0.5f * d * d : ad - 0.5f;
        d = p1.x - tv.w; ad = fabsf(d); accB += (ad < 1.f) ? 0.5f * d * d : ad - 0.5f;
        const int lab = tlabels[(size_t)b0 * kM + j];
        const float c0 = p1.y, c1 = p1.z, c2 = p1.w;
        const float mx = fmaxf(c0, fmaxf(c1, c2));
        const float lse = mx + __logf(__expf(c0 - mx) + __expf(c1 - mx) + __expf(c2 - mx));
        const float logit = (lab == 0) ? c0 : ((lab == 1) ? c1 : c2);
        const float cwv   = (lab == 0) ? cw0 : ((lab == 1) ? cw1 : cw2);
        accC += cwv * (lse - logit);
    }

    // ---- Block reduce (4 float sums) + plain SoA stores ----
    float vals[4] = {accO, accN, accB, accC};
    #pragma unroll
    for (int k = 0; k < 4; ++k) {
        float v = vals[k];
        #pragma unroll
        for (int off = 32; off > 0; off >>= 1) v += __shfl_down(v, off, 64);
        vals[k] = v;
    }
    const int wave = tid >> 6;
    const int lane = tid & 63;
    if (lane == 0) {
        #pragma unroll
        for (int k = 0; k < 4; ++k) s_red[wave][k] = vals[k];
    }
    __syncthreads();
    if (tid == 0) {
        #pragma unroll
        for (int k = 0; k < 4; ++k) {
            float t = 0.f;
            #pragma unroll
            for (int w = 0; w < kBlockA / 64; ++w) t += s_red[w][k];
            partial[(size_t)k * NT + blockIdx.x] = t;
        }
        partial[(size_t)4 * NT + blockIdx.x] = (float)np;   // num_pos
    }
}

// ---------------- Kernel B: pure noobj stream ----------------
__global__ __launch_bounds__(kBlockN) void det_loss_noobj(
    const float4* __restrict__ preds4,
    float* __restrict__ partial,   // owns cols [col0, col0+gridDim.x)
    long long n4, int NT, int col0)
{
    __shared__ float s_red[kBlockN / 64];
    const int tid = threadIdx.x;
    const long long gtid = (long long)blockIdx.x * kBlockN + tid;
    const long long stride = (long long)gridDim.x * kBlockN;   // even
    const bool hasObj = ((gtid & 1) == 0);   // chunk parity == gtid parity
    float acc = 0.f;
    long long i = gtid;
    // main unrolled-by-4 stretch (independent loads -> MLP)
    for (; i + 3 * stride < n4; i += 4 * stride) {
        const float4 v0 = preds4[i];
        const float4 v1 = preds4[i + stride];
        const float4 v2 = preds4[i + 2 * stride];
        const float4 v3 = preds4[i + 3 * stride];
        if (hasObj) {
            acc += softplus_fast(v0.x);
            acc += softplus_fast(v1.x);
            acc += softplus_fast(v2.x);
            acc += softplus_fast(v3.x);
        }
    }
    for (; i < n4; i += stride) {
        const float4 v = preds4[i];
        if (hasObj) acc += softplus_fast(v.x);
    }

    #pragma unroll
    for (int off = 32; off > 0; off >>= 1) acc += __shfl_down(acc, off, 64);
    if ((tid & 63) == 0) s_red[tid >> 6] = acc;
    __syncthreads();
    if (tid == 0) {
        float t = 0.f;
        #pragma unroll
        for (int w = 0; w < kBlockN / 64; ++w) t += s_red[w];
        const int col = col0 + blockIdx.x;
        partial[(size_t)0 * NT + col] = 0.f;
        partial[(size_t)1 * NT + col] = t;
        partial[(size_t)2 * NT + col] = 0.f;
        partial[(size_t)3 * NT + col] = 0.f;
        partial[(size_t)4 * NT + col] = 0.f;
    }
}

// ---------------- Reduce ----------------
__global__ __launch_bounds__(256) void det_loss_reduce(
    const float* __restrict__ partial, int NT, float* __restrict__ out)
{
    __shared__ float s_red[4][5];
    const int tid = threadIdx.x;
    float v[5] = {0.f, 0.f, 0.f, 0.f, 0.f};
    for (int i = tid; i < NT; i += 256) {
        #pragma unroll
        for (int k = 0; k < 5; ++k) v[k] += partial[(size_t)k * NT + i];
    }
    #pragma unroll
    for (int k = 0; k < 5; ++k) {
        float x = v[k];
        #pragma unroll
        for (int off = 32; off > 0; off >>= 1) x += __shfl_down(x, off, 64);
        v[k] = x;
    }
    const int wave = tid >> 6;
    const int lane = tid & 63;
    if (lane == 0) {
        #pragma unroll
        for (int k = 0; k < 5; ++k) s_red[wave][k] = v[k];
    }
    __syncthreads();
    if (tid == 0) {
        float t[5];
        #pragma unroll
        for (int k = 0; k < 5; ++k) {
            float s = 0.f;
            #pragma unroll
            for (int w = 0; w < 4; ++w) s += s_red[w][k];
            t[k] = s;
        }
        const float npv = fmaxf(t[4], 1.0f);
        out[0] = (5.0f * t[2] + 1.0f * t[0] + 0.5f * t[1] + 2.0f * t[3]) / npv;
    }
}

extern "C" void kernel_launch(void* const* d_in, const int* in_sizes, int n_in,
                              void* d_out, int out_size, void* d_ws, size_t ws_size,
                              hipStream_t stream) {
    const float* preds    = (const float*)d_in[0];
    const float* tboxes   = (const float*)d_in[1];
    const int*   tlabels  = (const int*)d_in[2];
    const int*   nobjs    = (const int*)d_in[3];
    const float* anchors  = (const float*)d_in[4];
    const float* cweights = (const float*)d_in[5];
    float* out = (float*)d_out;
    float* partial = (float*)d_ws;   // [5][NT], fully overwritten every call

    const int B = in_sizes[0] / (kCells * kCh);   // /784
    const int blocksA = (B + kNB - 1) / kNB;
    const int NT = blocksA + kGridN;
    const long long n4 = (long long)B * kCells * 2;   // float4 chunks in preds

    det_loss_assign<<<blocksA, kBlockA, 0, stream>>>(
        preds, tboxes, tlabels, nobjs, anchors, cweights, partial, B, NT);
    det_loss_noobj<<<kGridN, kBlockN, 0, stream>>>(
        (const float4*)preds, partial, n4, NT, blocksA);
    det_loss_reduce<<<1, 256, 0, stream>>>(partial, NT, out);
}